// Round 8
// baseline (326.049 us; speedup 1.0000x reference)
//
#include <hip/hip_runtime.h>
#include <hip/hip_fp16.h>

#define D 128
#define N_NODES 50000
#define EPSP1 1.1f

// ---- bucketed CSR-build parameters ----
#define NPB 256                 // nodes per bucket (dst >> 8)
#define NBUCK 196               // ceil(50000/256)
#define CAP 5120                // staging capacity per bucket (avg 4082)
#define P1E 2048                // edges per pass-1 block (8 per thread)
#define TS 136                  // LDS tile row stride (bf16 elems)

typedef __attribute__((ext_vector_type(8))) short short8;   // 8 bf16 (4 VGPRs)
typedef __attribute__((ext_vector_type(4))) float f32x4;    // MFMA accumulator

__device__ __forceinline__ unsigned short f2bf(float f) {
    unsigned u = __float_as_uint(f);
    u += 0x7FFF + ((u >> 16) & 1);          // round-to-nearest-even
    return (unsigned short)(u >> 16);
}
__device__ __forceinline__ float bf2f(unsigned short h) {
    return __uint_as_float(((unsigned)h) << 16);
}

// ---------------------------------------------------------------------------
// Fused pre-pass (independent work, branch by block range):
//   [0, p1grid)                  : pass-1 edge bucketing -> gstage
//   [p1grid, p1grid+cgrid)       : x fp32 -> bf16 (4096 elems/block)
//   [p1grid+cgrid, +32)          : pack 4 weight matrices to B-fragment order
// ---------------------------------------------------------------------------
__global__ __launch_bounds__(256) void fused_pre(
    const int* __restrict__ src, const int* __restrict__ dst,
    const float* __restrict__ ew, int* __restrict__ gcnt,
    uint2* __restrict__ gstage, int ne,
    const float* __restrict__ x, unsigned short* __restrict__ hb, int n4,
    const float* __restrict__ W1a, const float* __restrict__ W1b,
    const float* __restrict__ W2a, const float* __restrict__ W2b,
    unsigned short* __restrict__ wp, int p1grid, int cgrid)
{
    int bid = blockIdx.x;
    int tid = threadIdx.x;
    if (bid < p1grid) {
        __shared__ int bcnt[NBUCK];
        __shared__ int goff[NBUCK];
        if (tid < NBUCK) bcnt[tid] = 0;
        __syncthreads();
        int e0 = bid * P1E;
        int   rank[8];
        int   buck[8];
        uint2 pay[8];
#pragma unroll
        for (int j = 0; j < 8; ++j) {
            int e = e0 + j * 256 + tid;
            buck[j] = -1;
            if (e < ne) {
                int d_ = dst[e];
                int b  = d_ >> 8;
                int dl = d_ & 255;
                pay[j].x = (unsigned)(src[e] & 0xFFFF) | ((unsigned)dl << 16);
                pay[j].y = (unsigned)__half_as_ushort(__float2half_rn(ew[e]));
                rank[j]  = atomicAdd(&bcnt[b], 1);
                buck[j]  = b;
            }
        }
        __syncthreads();
        if (tid < NBUCK && bcnt[tid] > 0)
            goff[tid] = atomicAdd(&gcnt[tid], bcnt[tid]);
        __syncthreads();
#pragma unroll
        for (int j = 0; j < 8; ++j) {
            if (buck[j] >= 0) {
                int pos = goff[buck[j]] + rank[j];
                if (pos < CAP)
                    gstage[(size_t)buck[j] * CAP + pos] = pay[j];
            }
        }
    } else if (bid < p1grid + cgrid) {
        int base = (bid - p1grid) * 1024;      // in float4 units
#pragma unroll
        for (int it = 0; it < 4; ++it) {
            int i = base + it * 256 + tid;
            if (i < n4) {
                float4 v = ((const float4*)x)[i];
                ushort4 o;
                o.x = f2bf(v.x); o.y = f2bf(v.y); o.z = f2bf(v.z); o.w = f2bf(v.w);
                ((ushort4*)hb)[i] = o;
            }
        }
    } else {
        int pb = bid - p1grid - cgrid;         // 0..31
        int mat = pb >> 3;                     // 0..3
        const float* W = (mat == 0) ? W1a : (mat == 1) ? W1b : (mat == 2) ? W2a : W2b;
        unsigned short* Wp = wp + (size_t)mat * 16384;
        int e = (pb & 7) * 256 + tid;          // 0..2047
        int col = e & 127;
        int kq  = e >> 7;
        short8 v;
#pragma unroll
        for (int j = 0; j < 8; ++j)
            v[j] = (short)f2bf(W[(size_t)(kq * 8 + j) * 128 + col]);
        ((short8*)Wp)[e] = v;
    }
}

// ---------------------------------------------------------------------------
// Pass 2: per-bucket CSR build.  One block per bucket (512 threads).
// ---------------------------------------------------------------------------
__global__ __launch_bounds__(512) void csr_build(
    const uint2* __restrict__ gstage, const int* __restrict__ gcnt,
    unsigned* __restrict__ epay, int* __restrict__ off)
{
    __shared__ int hist[NPB];
    __shared__ int scan[NPB];
    __shared__ int bscan[NPB];
    __shared__ int loc[NPB];
    __shared__ unsigned csr[CAP];          // 20 KB

    int b = blockIdx.x;
    int t = threadIdx.x;
    int cnt = min(gcnt[b], CAP);

    if (t < NPB) hist[t] = 0;
    __syncthreads();

    uint2 ent[CAP / 512];                  // 10
#pragma unroll
    for (int it = 0; it < CAP / 512; ++it) {
        int i = it * 512 + t;
        if (i < cnt) {
            ent[it] = gstage[(size_t)b * CAP + i];
            atomicAdd(&hist[(ent[it].x >> 16) & 255], 1);
        }
    }
    __syncthreads();

    if (t < NPB) {
        scan[t]  = hist[t];
        bscan[t] = (t < b) ? min(gcnt[t], CAP) : 0;
    }
    __syncthreads();
    for (int dd = 1; dd < NPB; dd <<= 1) {
        int a0 = 0, a1 = 0;
        if (t < NPB && t >= dd) { a0 = scan[t - dd]; a1 = bscan[t - dd]; }
        __syncthreads();
        if (t < NPB && t >= dd) { scan[t] += a0; bscan[t] += a1; }
        __syncthreads();
    }
    int base = bscan[NPB - 1];

    if (t < NPB) {
        int node = (b << 8) + t;
        int excl = scan[t] - hist[t];
        if (node <= N_NODES) off[node] = base + excl;
        loc[t] = excl;
    }
    __syncthreads();

#pragma unroll
    for (int it = 0; it < CAP / 512; ++it) {
        int i = it * 512 + t;
        if (i < cnt) {
            int dl = (ent[it].x >> 16) & 255;
            int p = atomicAdd(&loc[dl], 1);
            csr[p] = (ent[it].x & 0xFFFF) | (ent[it].y << 16);
        }
    }
    __syncthreads();

    for (int i = t; i < cnt; i += 512)
        epay[base + i] = csr[i];
}

// ---------------------------------------------------------------------------
// Fully fused GIN conv:  out = act2( relu( z @ Wa ) @ Wb )
//   z[i] = 1.1*h[i] + sum_{e: dst=i} w_e * h[src(e)]   (computed per wave
//   into its own LDS tile rows, then consumed as MFMA A-fragments)
// Block: 256 threads = 4 waves, 128 rows; wave w owns rows w*32..w*32+31.
// Gather: two 32-lane halves, 4 edges in flight each (8 per wave).
// 16x16x32 bf16 MFMA; weights in packed B-fragment order (L2-served).
// ---------------------------------------------------------------------------
template<int RELU2, int OUT_F32>
__global__ __launch_bounds__(256) void gin_fused(
    const unsigned short* __restrict__ h, const int* __restrict__ off,
    const unsigned* __restrict__ epay,
    const unsigned short* __restrict__ WpA,
    const unsigned short* __restrict__ WpB,
    void* __restrict__ outv, int n)
{
    __shared__ unsigned short t[128 * TS];   // 34 KB

    int tid  = threadIdx.x;
    int wave = tid >> 6;
    int lane = tid & 63;
    int half = lane >> 5;
    int sub  = lane & 31;
    int quad = lane >> 4;
    int lc   = lane & 15;
    int rbase = blockIdx.x * 128 + wave * 32;
    int rloc  = wave * 32;

    // ---- phase 0: gather this wave's 32 node rows into LDS
    for (int j = 0; j < 32; ++j) {
        int node = rbase + j;                 // wave-uniform
        float4 acc = make_float4(0.f, 0.f, 0.f, 0.f);
        if (node < n) {
            int beg = off[node];
            int end = off[node + 1];
            int i = beg;
            for (; i + 8 <= end; i += 8) {    // 4 edges per half in flight
                unsigned p0 = epay[i + half];
                unsigned p1 = epay[i + 2 + half];
                unsigned p2 = epay[i + 4 + half];
                unsigned p3 = epay[i + 6 + half];
                ushort4 v0 = ((const ushort4*)(h + (size_t)(p0 & 0xFFFF) * D))[sub];
                ushort4 v1 = ((const ushort4*)(h + (size_t)(p1 & 0xFFFF) * D))[sub];
                ushort4 v2 = ((const ushort4*)(h + (size_t)(p2 & 0xFFFF) * D))[sub];
                ushort4 v3 = ((const ushort4*)(h + (size_t)(p3 & 0xFFFF) * D))[sub];
                float w0 = __half2float(__ushort_as_half((unsigned short)(p0 >> 16)));
                float w1 = __half2float(__ushort_as_half((unsigned short)(p1 >> 16)));
                float w2 = __half2float(__ushort_as_half((unsigned short)(p2 >> 16)));
                float w3 = __half2float(__ushort_as_half((unsigned short)(p3 >> 16)));
                acc.x += w0 * bf2f(v0.x) + w1 * bf2f(v1.x) + w2 * bf2f(v2.x) + w3 * bf2f(v3.x);
                acc.y += w0 * bf2f(v0.y) + w1 * bf2f(v1.y) + w2 * bf2f(v2.y) + w3 * bf2f(v3.y);
                acc.z += w0 * bf2f(v0.z) + w1 * bf2f(v1.z) + w2 * bf2f(v2.z) + w3 * bf2f(v3.z);
                acc.w += w0 * bf2f(v0.w) + w1 * bf2f(v1.w) + w2 * bf2f(v2.w) + w3 * bf2f(v3.w);
            }
            for (; i + half < end; i += 2) {  // tail, per-half predicated
                unsigned p0 = epay[i + half];
                ushort4 v0 = ((const ushort4*)(h + (size_t)(p0 & 0xFFFF) * D))[sub];
                float w0 = __half2float(__ushort_as_half((unsigned short)(p0 >> 16)));
                acc.x += w0 * bf2f(v0.x);
                acc.y += w0 * bf2f(v0.y);
                acc.z += w0 * bf2f(v0.z);
                acc.w += w0 * bf2f(v0.w);
            }
        }
        // combine halves (lanes 0..31 pull 32..63)
        acc.x += __shfl(acc.x, sub + 32, 64);
        acc.y += __shfl(acc.y, sub + 32, 64);
        acc.z += __shfl(acc.z, sub + 32, 64);
        acc.w += __shfl(acc.w, sub + 32, 64);
        if (half == 0) {
            if (node < n) {
                ushort4 xv = ((const ushort4*)(h + (size_t)node * D))[sub];
                acc.x += EPSP1 * bf2f(xv.x);
                acc.y += EPSP1 * bf2f(xv.y);
                acc.z += EPSP1 * bf2f(xv.z);
                acc.w += EPSP1 * bf2f(xv.w);
            } else {
                acc = make_float4(0.f, 0.f, 0.f, 0.f);
            }
            ushort4 o;
            o.x = f2bf(acc.x); o.y = f2bf(acc.y); o.z = f2bf(acc.z); o.w = f2bf(acc.w);
            *(ushort4*)&t[(rloc + j) * TS + sub * 4] = o;
        }
    }
    __syncthreads();

    // ---- phase 1: GEMM1 (A from LDS, own rows)
    short8 a[2][4];
#pragma unroll
    for (int s = 0; s < 2; ++s) {
        int row = rloc + s * 16 + lc;
#pragma unroll
        for (int kk = 0; kk < 4; ++kk)
            a[s][kk] = *(const short8*)&t[row * TS + kk * 32 + quad * 8];
    }

    f32x4 acc[2][8];
#pragma unroll
    for (int s = 0; s < 2; ++s)
#pragma unroll
        for (int c = 0; c < 8; ++c)
            acc[s][c] = (f32x4){0.f, 0.f, 0.f, 0.f};

#pragma unroll
    for (int cf = 0; cf < 8; ++cf) {
        short8 b[4];
#pragma unroll
        for (int kk = 0; kk < 4; ++kk)
            b[kk] = *(const short8*)(WpA + ((size_t)(kk * 4 + quad) * 128 + cf * 16 + lc) * 8);
#pragma unroll
        for (int kk = 0; kk < 4; ++kk) {
            acc[0][cf] = __builtin_amdgcn_mfma_f32_16x16x32_bf16(a[0][kk], b[kk], acc[0][cf], 0, 0, 0);
            acc[1][cf] = __builtin_amdgcn_mfma_f32_16x16x32_bf16(a[1][kk], b[kk], acc[1][cf], 0, 0, 0);
        }
    }

    // ---- epilogue 1: relu -> bf16 back into own LDS rows
#pragma unroll
    for (int s = 0; s < 2; ++s)
#pragma unroll
        for (int reg = 0; reg < 4; ++reg) {
            int row = rloc + s * 16 + quad * 4 + reg;
#pragma unroll
            for (int cf = 0; cf < 8; ++cf)
                t[row * TS + cf * 16 + lc] = f2bf(fmaxf(acc[s][cf][reg], 0.f));
        }
    __syncthreads();

    // ---- phase 2: GEMM2 (A from LDS, own rows)
#pragma unroll
    for (int s = 0; s < 2; ++s) {
        int row = rloc + s * 16 + lc;
#pragma unroll
        for (int kk = 0; kk < 4; ++kk)
            a[s][kk] = *(const short8*)&t[row * TS + kk * 32 + quad * 8];
    }
#pragma unroll
    for (int s = 0; s < 2; ++s)
#pragma unroll
        for (int c = 0; c < 8; ++c)
            acc[s][c] = (f32x4){0.f, 0.f, 0.f, 0.f};

#pragma unroll
    for (int cf = 0; cf < 8; ++cf) {
        short8 b[4];
#pragma unroll
        for (int kk = 0; kk < 4; ++kk)
            b[kk] = *(const short8*)(WpB + ((size_t)(kk * 4 + quad) * 128 + cf * 16 + lc) * 8);
#pragma unroll
        for (int kk = 0; kk < 4; ++kk) {
            acc[0][cf] = __builtin_amdgcn_mfma_f32_16x16x32_bf16(a[0][kk], b[kk], acc[0][cf], 0, 0, 0);
            acc[1][cf] = __builtin_amdgcn_mfma_f32_16x16x32_bf16(a[1][kk], b[kk], acc[1][cf], 0, 0, 0);
        }
    }

    // ---- epilogue 2: optional relu, store global
#pragma unroll
    for (int s = 0; s < 2; ++s)
#pragma unroll
        for (int reg = 0; reg < 4; ++reg) {
            int row = rbase + s * 16 + quad * 4 + reg;
            if (row < n) {
#pragma unroll
                for (int cf = 0; cf < 8; ++cf) {
                    float v = acc[s][cf][reg];
                    if (RELU2) v = fmaxf(v, 0.f);
                    int col = cf * 16 + lc;
                    if (OUT_F32)
                        ((float*)outv)[(size_t)row * D + col] = v;
                    else
                        ((unsigned short*)outv)[(size_t)row * D + col] = f2bf(v);
                }
            }
        }
}

extern "C" void kernel_launch(void* const* d_in, const int* in_sizes, int n_in,
                              void* d_out, int out_size, void* d_ws, size_t ws_size,
                              hipStream_t stream) {
    const float* x   = (const float*)d_in[0];
    const int*   ei  = (const int*)d_in[1];
    const float* ew  = (const float*)d_in[2];
    const float* W1a = (const float*)d_in[3];
    const float* W1b = (const float*)d_in[4];
    const float* W2a = (const float*)d_in[5];
    const float* W2b = (const float*)d_in[6];
    float* out = (float*)d_out;

    int n_edges = in_sizes[2];                 // 800000
    const int* src = ei;
    const int* dst = ei + n_edges;

    size_t node_elems = (size_t)N_NODES * D;   // 6.4M
    unsigned short* hb = (unsigned short*)d_ws;        // 12.8 MB  bf16 x
    unsigned short* h2 = hb + node_elems;              // 12.8 MB  conv1 output
    unsigned short* wp = h2 + node_elems;              // 4 x 32 KB packed weights
    unsigned* epay = (unsigned*)(wp + 4 * 16384);      // E x 4B final CSR payload
    uint2*  gstage = (uint2*)(epay + n_edges);         // NBUCK x CAP x 8B staging
    int*    gcnt   = (int*)(gstage + (size_t)NBUCK * CAP);  // NBUCK
    int*    off    = gcnt + NBUCK;                     // N+1

    int p1grid = (n_edges + P1E - 1) / P1E;             // 391
    int cgrid  = ((int)(node_elems / 4) + 1023) / 1024; // 1563
    int ggrid  = (N_NODES + 127) / 128;                 // 391

    hipMemsetAsync(gcnt, 0, NBUCK * sizeof(int), stream);

    fused_pre<<<p1grid + cgrid + 32, 256, 0, stream>>>(
        src, dst, ew, gcnt, gstage, n_edges,
        x, hb, (int)(node_elems / 4),
        W1a, W1b, W2a, W2b, wp, p1grid, cgrid);

    csr_build<<<NBUCK, 512, 0, stream>>>(gstage, gcnt, epay, off);

    unsigned short* wp0 = wp;
    unsigned short* wp1 = wp + 16384;
    unsigned short* wp2 = wp + 2 * 16384;
    unsigned short* wp3 = wp + 3 * 16384;

    // ---- conv 1 (gather + MLP + inter-conv relu, one kernel)
    gin_fused<1, 0><<<ggrid, 256, 0, stream>>>(hb, off, epay, wp0, wp1, h2, N_NODES);
    // ---- conv 2 (fp32 out, no final relu)
    gin_fused<0, 1><<<ggrid, 256, 0, stream>>>(h2, off, epay, wp2, wp3, out, N_NODES);
}

// Round 9
// 201.470 us; speedup vs baseline: 1.6184x; 1.6184x over previous
//
#include <hip/hip_runtime.h>
#include <hip/hip_fp16.h>

#define D 128
#define N_NODES 50000
#define EPSP1 1.1f

// ---- bucketed CSR-build parameters ----
#define NPB 256                 // nodes per bucket (dst >> 8)
#define NBUCK 196               // ceil(50000/256)
#define CAP 5120                // staging capacity per bucket (avg 4082)
#define P1E 2048                // edges per pass-1 block (8 per thread)
#define TS 136                  // LDS tile row stride (bf16 elems)

typedef __attribute__((ext_vector_type(8))) short short8;   // 8 bf16 (4 VGPRs)
typedef __attribute__((ext_vector_type(4))) float f32x4;    // MFMA accumulator

__device__ __forceinline__ unsigned short f2bf(float f) {
    unsigned u = __float_as_uint(f);
    u += 0x7FFF + ((u >> 16) & 1);          // round-to-nearest-even
    return (unsigned short)(u >> 16);
}
__device__ __forceinline__ float bf2f(unsigned short h) {
    return __uint_as_float(((unsigned)h) << 16);
}

// ---------------------------------------------------------------------------
// Fused pre-pass (independent work, branch by block range):
//   [0, p1grid)                  : pass-1 edge bucketing -> gstage
//   [p1grid, p1grid+cgrid)       : x fp32 -> bf16 (4096 elems/block)
//   [p1grid+cgrid, +32)          : pack 4 weight matrices to B-fragment order
// ---------------------------------------------------------------------------
__global__ __launch_bounds__(256) void fused_pre(
    const int* __restrict__ src, const int* __restrict__ dst,
    const float* __restrict__ ew, int* __restrict__ gcnt,
    uint2* __restrict__ gstage, int ne,
    const float* __restrict__ x, unsigned short* __restrict__ hb, int n4,
    const float* __restrict__ W1a, const float* __restrict__ W1b,
    const float* __restrict__ W2a, const float* __restrict__ W2b,
    unsigned short* __restrict__ wp, int p1grid, int cgrid)
{
    int bid = blockIdx.x;
    int tid = threadIdx.x;
    if (bid < p1grid) {
        __shared__ int bcnt[NBUCK];
        __shared__ int goff[NBUCK];
        if (tid < NBUCK) bcnt[tid] = 0;
        __syncthreads();
        int e0 = bid * P1E;
        int   rank[8];
        int   buck[8];
        uint2 pay[8];
#pragma unroll
        for (int j = 0; j < 8; ++j) {
            int e = e0 + j * 256 + tid;
            buck[j] = -1;
            if (e < ne) {
                int d_ = dst[e];
                int b  = d_ >> 8;
                int dl = d_ & 255;
                pay[j].x = (unsigned)(src[e] & 0xFFFF) | ((unsigned)dl << 16);
                pay[j].y = (unsigned)__half_as_ushort(__float2half_rn(ew[e]));
                rank[j]  = atomicAdd(&bcnt[b], 1);
                buck[j]  = b;
            }
        }
        __syncthreads();
        if (tid < NBUCK && bcnt[tid] > 0)
            goff[tid] = atomicAdd(&gcnt[tid], bcnt[tid]);
        __syncthreads();
#pragma unroll
        for (int j = 0; j < 8; ++j) {
            if (buck[j] >= 0) {
                int pos = goff[buck[j]] + rank[j];
                if (pos < CAP)
                    gstage[(size_t)buck[j] * CAP + pos] = pay[j];
            }
        }
    } else if (bid < p1grid + cgrid) {
        int base = (bid - p1grid) * 1024;      // in float4 units
#pragma unroll
        for (int it = 0; it < 4; ++it) {
            int i = base + it * 256 + tid;
            if (i < n4) {
                float4 v = ((const float4*)x)[i];
                ushort4 o;
                o.x = f2bf(v.x); o.y = f2bf(v.y); o.z = f2bf(v.z); o.w = f2bf(v.w);
                ((ushort4*)hb)[i] = o;
            }
        }
    } else {
        int pb = bid - p1grid - cgrid;         // 0..31
        int mat = pb >> 3;                     // 0..3
        const float* W = (mat == 0) ? W1a : (mat == 1) ? W1b : (mat == 2) ? W2a : W2b;
        unsigned short* Wp = wp + (size_t)mat * 16384;
        int e = (pb & 7) * 256 + tid;          // 0..2047
        int col = e & 127;
        int kq  = e >> 7;
        short8 v;
#pragma unroll
        for (int j = 0; j < 8; ++j)
            v[j] = (short)f2bf(W[(size_t)(kq * 8 + j) * 128 + col]);
        ((short8*)Wp)[e] = v;
    }
}

// ---------------------------------------------------------------------------
// Pass 2: per-bucket CSR build.  One block per bucket (512 threads).
// ---------------------------------------------------------------------------
__global__ __launch_bounds__(512) void csr_build(
    const uint2* __restrict__ gstage, const int* __restrict__ gcnt,
    unsigned* __restrict__ epay, int* __restrict__ off)
{
    __shared__ int hist[NPB];
    __shared__ int scan[NPB];
    __shared__ int bscan[NPB];
    __shared__ int loc[NPB];
    __shared__ unsigned csr[CAP];          // 20 KB

    int b = blockIdx.x;
    int t = threadIdx.x;
    int cnt = min(gcnt[b], CAP);

    if (t < NPB) hist[t] = 0;
    __syncthreads();

    uint2 ent[CAP / 512];                  // 10
#pragma unroll
    for (int it = 0; it < CAP / 512; ++it) {
        int i = it * 512 + t;
        if (i < cnt) {
            ent[it] = gstage[(size_t)b * CAP + i];
            atomicAdd(&hist[(ent[it].x >> 16) & 255], 1);
        }
    }
    __syncthreads();

    if (t < NPB) {
        scan[t]  = hist[t];
        bscan[t] = (t < b) ? min(gcnt[t], CAP) : 0;
    }
    __syncthreads();
    for (int dd = 1; dd < NPB; dd <<= 1) {
        int a0 = 0, a1 = 0;
        if (t < NPB && t >= dd) { a0 = scan[t - dd]; a1 = bscan[t - dd]; }
        __syncthreads();
        if (t < NPB && t >= dd) { scan[t] += a0; bscan[t] += a1; }
        __syncthreads();
    }
    int base = bscan[NPB - 1];

    if (t < NPB) {
        int node = (b << 8) + t;
        int excl = scan[t] - hist[t];
        if (node <= N_NODES) off[node] = base + excl;
        loc[t] = excl;
    }
    __syncthreads();

#pragma unroll
    for (int it = 0; it < CAP / 512; ++it) {
        int i = it * 512 + t;
        if (i < cnt) {
            int dl = (ent[it].x >> 16) & 255;
            int p = atomicAdd(&loc[dl], 1);
            csr[p] = (ent[it].x & 0xFFFF) | (ent[it].y << 16);
        }
    }
    __syncthreads();

    for (int i = t; i < cnt; i += 512)
        epay[base + i] = csr[i];
}

// ---------------------------------------------------------------------------
// Gather-aggregate (bf16, fp32 accumulate) + fused GIN update.
// One wave per node; FOUR 16-lane quarters, each takes one edge per step
// (ushort8 = 16B/lane x 16 lanes = 256B row).  2x unroll -> 8 rows in flight.
// Quarter-combine via two shuffles.
// ---------------------------------------------------------------------------
__global__ __launch_bounds__(256) void gather_kernel(
    const unsigned short* __restrict__ h, const int* __restrict__ off,
    const unsigned* __restrict__ epay, unsigned short* __restrict__ z, int n_nodes)
{
    int tid = threadIdx.x;
    int node = blockIdx.x * 4 + (tid >> 6);
    if (node >= n_nodes) return;
    int lane = tid & 63;
    int qtr  = lane >> 4;       // 0..3
    int sub  = lane & 15;       // element group: 16B per lane
    int beg = off[node];
    int end = off[node + 1];
    float acc[8];
#pragma unroll
    for (int c = 0; c < 8; ++c) acc[c] = 0.f;

    int i = beg;
    for (; i + 8 <= end; i += 8) {        // 8 rows in flight per wave
        unsigned p0 = epay[i + qtr];
        unsigned p1 = epay[i + 4 + qtr];
        short8 v0 = ((const short8*)(h + (size_t)(p0 & 0xFFFF) * D))[sub];
        short8 v1 = ((const short8*)(h + (size_t)(p1 & 0xFFFF) * D))[sub];
        float w0 = __half2float(__ushort_as_half((unsigned short)(p0 >> 16)));
        float w1 = __half2float(__ushort_as_half((unsigned short)(p1 >> 16)));
#pragma unroll
        for (int c = 0; c < 8; ++c)
            acc[c] += w0 * bf2f((unsigned short)v0[c]) + w1 * bf2f((unsigned short)v1[c]);
    }
    for (; i + qtr < end; i += 4) {       // tail, per-quarter predicated
        unsigned p0 = epay[i + qtr];
        short8 v0 = ((const short8*)(h + (size_t)(p0 & 0xFFFF) * D))[sub];
        float w0 = __half2float(__ushort_as_half((unsigned short)(p0 >> 16)));
#pragma unroll
        for (int c = 0; c < 8; ++c)
            acc[c] += w0 * bf2f((unsigned short)v0[c]);
    }

    // combine quarters: after two steps lanes 0..15 hold the full sum
#pragma unroll
    for (int c = 0; c < 8; ++c) {
        acc[c] += __shfl(acc[c], (lane + 32) & 63, 64);
        acc[c] += __shfl(acc[c], (lane + 16) & 63, 64);
    }

    if (qtr == 0) {
        short8 xv = ((const short8*)(h + (size_t)node * D))[sub];
        short8 o;
#pragma unroll
        for (int c = 0; c < 8; ++c) {
            float v = acc[c] + EPSP1 * bf2f((unsigned short)xv[c]);
            o[c] = (short)f2bf(v);
        }
        ((short8*)(z + (size_t)node * D))[sub] = o;
    }
}

// ---------------------------------------------------------------------------
// Fused 2-layer MLP: out = act2( relu( A @ Wa ) @ Wb )
// Per block: 128 rows; 4 waves, each 32 rows x 128 cols.  GEMM1 -> LDS tile
// (bf16, stride TS) -> GEMM2.  16x16x32 bf16 MFMA; weights in packed
// B-fragment order (L2-served).
// ---------------------------------------------------------------------------
template<int RELU2, int OUT_F32>
__global__ __launch_bounds__(256) void mlp_fused(
    const unsigned short* __restrict__ A,
    const unsigned short* __restrict__ WpA,
    const unsigned short* __restrict__ WpB,
    void* __restrict__ outv, int n)
{
    __shared__ unsigned short t[128 * TS];   // 34 KB

    int tid  = threadIdx.x;
    int wave = tid >> 6;
    int lane = tid & 63;
    int quad = lane >> 4;
    int lc   = lane & 15;
    int rbase = blockIdx.x * 128 + wave * 32;
    int rloc  = wave * 32;

    const short8 zero8 = {0, 0, 0, 0, 0, 0, 0, 0};

    short8 a[2][4];
#pragma unroll
    for (int s = 0; s < 2; ++s) {
        int row = rbase + s * 16 + lc;
        const unsigned short* ap = A + (size_t)row * D;
#pragma unroll
        for (int kk = 0; kk < 4; ++kk)
            a[s][kk] = (row < n) ? *(const short8*)(ap + kk * 32 + quad * 8) : zero8;
    }

    f32x4 acc[2][8];
#pragma unroll
    for (int s = 0; s < 2; ++s)
#pragma unroll
        for (int c = 0; c < 8; ++c)
            acc[s][c] = (f32x4){0.f, 0.f, 0.f, 0.f};

#pragma unroll
    for (int cf = 0; cf < 8; ++cf) {
        short8 b[4];
#pragma unroll
        for (int kk = 0; kk < 4; ++kk)
            b[kk] = *(const short8*)(WpA + ((size_t)(kk * 4 + quad) * 128 + cf * 16 + lc) * 8);
#pragma unroll
        for (int kk = 0; kk < 4; ++kk) {
            acc[0][cf] = __builtin_amdgcn_mfma_f32_16x16x32_bf16(a[0][kk], b[kk], acc[0][cf], 0, 0, 0);
            acc[1][cf] = __builtin_amdgcn_mfma_f32_16x16x32_bf16(a[1][kk], b[kk], acc[1][cf], 0, 0, 0);
        }
    }

#pragma unroll
    for (int s = 0; s < 2; ++s)
#pragma unroll
        for (int reg = 0; reg < 4; ++reg) {
            int row = rloc + s * 16 + quad * 4 + reg;
#pragma unroll
            for (int cf = 0; cf < 8; ++cf)
                t[row * TS + cf * 16 + lc] = f2bf(fmaxf(acc[s][cf][reg], 0.f));
        }
    __syncthreads();

#pragma unroll
    for (int s = 0; s < 2; ++s) {
        int row = rloc + s * 16 + lc;
#pragma unroll
        for (int kk = 0; kk < 4; ++kk)
            a[s][kk] = *(const short8*)&t[row * TS + kk * 32 + quad * 8];
    }
#pragma unroll
    for (int s = 0; s < 2; ++s)
#pragma unroll
        for (int c = 0; c < 8; ++c)
            acc[s][c] = (f32x4){0.f, 0.f, 0.f, 0.f};

#pragma unroll
    for (int cf = 0; cf < 8; ++cf) {
        short8 b[4];
#pragma unroll
        for (int kk = 0; kk < 4; ++kk)
            b[kk] = *(const short8*)(WpB + ((size_t)(kk * 4 + quad) * 128 + cf * 16 + lc) * 8);
#pragma unroll
        for (int kk = 0; kk < 4; ++kk) {
            acc[0][cf] = __builtin_amdgcn_mfma_f32_16x16x32_bf16(a[0][kk], b[kk], acc[0][cf], 0, 0, 0);
            acc[1][cf] = __builtin_amdgcn_mfma_f32_16x16x32_bf16(a[1][kk], b[kk], acc[1][cf], 0, 0, 0);
        }
    }

#pragma unroll
    for (int s = 0; s < 2; ++s)
#pragma unroll
        for (int reg = 0; reg < 4; ++reg) {
            int row = rbase + s * 16 + quad * 4 + reg;
            if (row < n) {
#pragma unroll
                for (int cf = 0; cf < 8; ++cf) {
                    float v = acc[s][cf][reg];
                    if (RELU2) v = fmaxf(v, 0.f);
                    int col = cf * 16 + lc;
                    if (OUT_F32)
                        ((float*)outv)[(size_t)row * D + col] = v;
                    else
                        ((unsigned short*)outv)[(size_t)row * D + col] = f2bf(v);
                }
            }
        }
}

extern "C" void kernel_launch(void* const* d_in, const int* in_sizes, int n_in,
                              void* d_out, int out_size, void* d_ws, size_t ws_size,
                              hipStream_t stream) {
    const float* x   = (const float*)d_in[0];
    const int*   ei  = (const int*)d_in[1];
    const float* ew  = (const float*)d_in[2];
    const float* W1a = (const float*)d_in[3];
    const float* W1b = (const float*)d_in[4];
    const float* W2a = (const float*)d_in[5];
    const float* W2b = (const float*)d_in[6];
    float* out = (float*)d_out;

    int n_edges = in_sizes[2];                 // 800000
    const int* src = ei;
    const int* dst = ei + n_edges;

    size_t node_elems = (size_t)N_NODES * D;   // 6.4M
    unsigned short* hb = (unsigned short*)d_ws;        // 12.8 MB  bf16 node features
    unsigned short* zb = hb + node_elems;              // 12.8 MB  gather output
    unsigned short* wp = zb + node_elems;              // 4 x 32 KB packed weights
    unsigned* epay = (unsigned*)(wp + 4 * 16384);      // E x 4B final CSR payload
    uint2*  gstage = (uint2*)(epay + n_edges);         // NBUCK x CAP x 8B staging
    int*    gcnt   = (int*)(gstage + (size_t)NBUCK * CAP);  // NBUCK
    int*    off    = gcnt + NBUCK;                     // N+1

    int p1grid = (n_edges + P1E - 1) / P1E;             // 391
    int cgrid  = ((int)(node_elems / 4) + 1023) / 1024; // 1563
    int ggrid  = (N_NODES + 127) / 128;                 // 391
    int agrid  = (N_NODES + 3) / 4;                     // 12500

    hipMemsetAsync(gcnt, 0, NBUCK * sizeof(int), stream);

    fused_pre<<<p1grid + cgrid + 32, 256, 0, stream>>>(
        src, dst, ew, gcnt, gstage, n_edges,
        x, hb, (int)(node_elems / 4),
        W1a, W1b, W2a, W2b, wp, p1grid, cgrid);

    csr_build<<<NBUCK, 512, 0, stream>>>(gstage, gcnt, epay, off);

    unsigned short* wp0 = wp;
    unsigned short* wp1 = wp + 16384;
    unsigned short* wp2 = wp + 2 * 16384;
    unsigned short* wp3 = wp + 3 * 16384;

    // ---- conv 1 (inter-conv relu fused into epilogue 2)
    gather_kernel<<<agrid, 256, 0, stream>>>(hb, off, epay, zb, N_NODES);
    mlp_fused<1, 0><<<ggrid, 256, 0, stream>>>(zb, wp0, wp1, hb, N_NODES);

    // ---- conv 2 (fp32 out, no final relu)
    gather_kernel<<<agrid, 256, 0, stream>>>(hb, off, epay, zb, N_NODES);
    mlp_fused<0, 1><<<ggrid, 256, 0, stream>>>(zb, wp2, wp3, out, N_NODES);
}

// Round 10
// 201.369 us; speedup vs baseline: 1.6192x; 1.0005x over previous
//
#include <hip/hip_runtime.h>
#include <hip/hip_fp16.h>

#define D 128
#define N_NODES 50000
#define EPSP1 1.1f

// ---- bucketed CSR-build parameters ----
#define NPB 256                 // nodes per bucket (dst >> 8)
#define NBUCK 196               // ceil(50000/256)
#define CAP 5120                // staging capacity per bucket (avg 4082)
#define P1E 2048                // edges per pass-1 block (8 per thread)
#define TS 136                  // LDS tile row stride (bf16 elems)

typedef __attribute__((ext_vector_type(8))) short short8;   // 8 bf16 (4 VGPRs)
typedef __attribute__((ext_vector_type(4))) float f32x4;    // MFMA accumulator

__device__ __forceinline__ unsigned short f2bf(float f) {
    unsigned u = __float_as_uint(f);
    u += 0x7FFF + ((u >> 16) & 1);          // round-to-nearest-even
    return (unsigned short)(u >> 16);
}
__device__ __forceinline__ float bf2f(unsigned short h) {
    return __uint_as_float(((unsigned)h) << 16);
}

// ---------------------------------------------------------------------------
// Pass 1: edge bucketing.  Per block: LDS-rank 2048 edges into 196 buckets,
// one global atomic per bucket per block, store 8B staged entries.
// ---------------------------------------------------------------------------
__global__ __launch_bounds__(256) void pass1_bucket(
    const int* __restrict__ src, const int* __restrict__ dst,
    const float* __restrict__ ew, int* __restrict__ gcnt,
    uint2* __restrict__ gstage, int ne)
{
    __shared__ int bcnt[NBUCK];
    __shared__ int goff[NBUCK];
    int tid = threadIdx.x;
    int bid = blockIdx.x;
    if (tid < NBUCK) bcnt[tid] = 0;
    __syncthreads();
    int e0 = bid * P1E;
    int   rank[8];
    int   buck[8];
    uint2 pay[8];
#pragma unroll
    for (int j = 0; j < 8; ++j) {
        int e = e0 + j * 256 + tid;
        buck[j] = -1;
        if (e < ne) {
            int d_ = dst[e];
            int b  = d_ >> 8;
            int dl = d_ & 255;
            pay[j].x = (unsigned)(src[e] & 0xFFFF) | ((unsigned)dl << 16);
            pay[j].y = (unsigned)__half_as_ushort(__float2half_rn(ew[e]));
            rank[j]  = atomicAdd(&bcnt[b], 1);
            buck[j]  = b;
        }
    }
    __syncthreads();
    if (tid < NBUCK && bcnt[tid] > 0)
        goff[tid] = atomicAdd(&gcnt[tid], bcnt[tid]);
    __syncthreads();
#pragma unroll
    for (int j = 0; j < 8; ++j) {
        if (buck[j] >= 0) {
            int pos = goff[buck[j]] + rank[j];
            if (pos < CAP)
                gstage[(size_t)buck[j] * CAP + pos] = pay[j];
        }
    }
}

// ---------------------------------------------------------------------------
// Fused mid-pass, 512 threads (independent work, branch by block range):
//   [0, NBUCK)            : per-bucket CSR build (shuffle-scan version)
//   [NBUCK, NBUCK+782)    : x fp32 -> bf16 (2048 float4 / block)
//   [NBUCK+782, +16)      : pack 4 weight matrices to B-fragment order
// The convert/pack blocks fill the CUs left idle by the 196 CSR blocks.
// ---------------------------------------------------------------------------
__global__ __launch_bounds__(512) void fused_mid(
    const uint2* __restrict__ gstage, const int* __restrict__ gcnt,
    unsigned* __restrict__ epay, int* __restrict__ off,
    const float* __restrict__ x, unsigned short* __restrict__ hb, int n4,
    const float* __restrict__ W1a, const float* __restrict__ W1b,
    const float* __restrict__ W2a, const float* __restrict__ W2b,
    unsigned short* __restrict__ wp)
{
    __shared__ int hist[NPB];
    __shared__ int scn[NPB];
    __shared__ int loc[NPB];
    __shared__ int wtot[8];
    __shared__ int base_s;
    __shared__ unsigned csr[CAP];          // 20 KB

    int bid = blockIdx.x;
    int t = threadIdx.x;

    if (bid < NBUCK) {
        // ================= CSR build for bucket b =================
        int b = bid;
        int cnt = min(gcnt[b], CAP);

        if (t < NPB) hist[t] = 0;
        __syncthreads();

        uint2 ent[CAP / 512];              // 10
#pragma unroll
        for (int it = 0; it < CAP / 512; ++it) {
            int i = it * 512 + t;
            if (i < cnt) {
                ent[it] = gstage[(size_t)b * CAP + i];
                atomicAdd(&hist[(ent[it].x >> 16) & 255], 1);
            }
        }
        __syncthreads();

        int w = t >> 6, l = t & 63;
        if (w < 4) {
            // waves 0-3: inclusive shuffle-scan of hist[w*64 .. w*64+63]
            int v = hist[w * 64 + l];
#pragma unroll
            for (int dd = 1; dd < 64; dd <<= 1) {
                int u = __shfl_up(v, dd, 64);
                if (l >= dd) v += u;
            }
            scn[w * 64 + l] = v;
            if (l == 63) wtot[w] = v;
        } else if (w == 4) {
            // wave 4: base = sum of preceding bucket counts
            int v = 0;
            for (int i = l; i < NBUCK; i += 64)
                if (i < b) v += min(gcnt[i], CAP);
#pragma unroll
            for (int dd = 32; dd > 0; dd >>= 1) v += __shfl_down(v, dd, 64);
            if (l == 0) base_s = v;
        }
        __syncthreads();

        if (t < NPB) {
            int pre = 0;
#pragma unroll
            for (int j = 0; j < 3; ++j) if (j < w) pre += wtot[j];
            int incl = scn[t] + pre;
            int excl = incl - hist[t];
            int node = (b << 8) + t;
            if (node <= N_NODES) off[node] = base_s + excl;
            loc[t] = excl;
        }
        __syncthreads();

#pragma unroll
        for (int it = 0; it < CAP / 512; ++it) {
            int i = it * 512 + t;
            if (i < cnt) {
                int dl = (ent[it].x >> 16) & 255;
                int p = atomicAdd(&loc[dl], 1);
                csr[p] = (ent[it].x & 0xFFFF) | (ent[it].y << 16);
            }
        }
        __syncthreads();

        for (int i = t; i < cnt; i += 512)
            epay[base_s + i] = csr[i];
    } else if (bid < NBUCK + 782) {
        // ================= x fp32 -> bf16 =================
        int base = (bid - NBUCK) * 2048;   // float4 units
#pragma unroll
        for (int it = 0; it < 4; ++it) {
            int i = base + it * 512 + t;
            if (i < n4) {
                float4 v = ((const float4*)x)[i];
                ushort4 o;
                o.x = f2bf(v.x); o.y = f2bf(v.y); o.z = f2bf(v.z); o.w = f2bf(v.w);
                ((ushort4*)hb)[i] = o;
            }
        }
    } else {
        // ================= weight pack =================
        int e2 = (bid - NBUCK - 782) * 512 + t;   // 0..8191
        int mat = e2 >> 11;                       // 0..3
        int e   = e2 & 2047;
        const float* W = (mat == 0) ? W1a : (mat == 1) ? W1b : (mat == 2) ? W2a : W2b;
        unsigned short* Wp = wp + (size_t)mat * 16384;
        int col = e & 127;
        int kq  = e >> 7;
        short8 v;
#pragma unroll
        for (int j = 0; j < 8; ++j)
            v[j] = (short)f2bf(W[(size_t)(kq * 8 + j) * 128 + col]);
        ((short8*)Wp)[e] = v;
    }
}

// ---------------------------------------------------------------------------
// Gather-aggregate (bf16, fp32 accumulate) + fused GIN update.
// One wave per node; FOUR 16-lane quarters, each one edge per step
// (ushort8 = 16B/lane x 16 lanes = 256B row).  Main step: 16 rows in flight.
// ---------------------------------------------------------------------------
__global__ __launch_bounds__(256) void gather_kernel(
    const unsigned short* __restrict__ h, const int* __restrict__ off,
    const unsigned* __restrict__ epay, unsigned short* __restrict__ z, int n_nodes)
{
    int tid = threadIdx.x;
    int node = blockIdx.x * 4 + (tid >> 6);
    if (node >= n_nodes) return;
    int lane = tid & 63;
    int qtr  = lane >> 4;       // 0..3
    int sub  = lane & 15;       // 16B per lane
    int beg = off[node];
    int end = off[node + 1];
    float acc[8];
#pragma unroll
    for (int c = 0; c < 8; ++c) acc[c] = 0.f;

    int i = beg;
    for (; i + 16 <= end; i += 16) {       // 16 rows in flight per wave
        unsigned p0 = epay[i + qtr];
        unsigned p1 = epay[i + 4 + qtr];
        unsigned p2 = epay[i + 8 + qtr];
        unsigned p3 = epay[i + 12 + qtr];
        short8 v0 = ((const short8*)(h + (size_t)(p0 & 0xFFFF) * D))[sub];
        short8 v1 = ((const short8*)(h + (size_t)(p1 & 0xFFFF) * D))[sub];
        short8 v2 = ((const short8*)(h + (size_t)(p2 & 0xFFFF) * D))[sub];
        short8 v3 = ((const short8*)(h + (size_t)(p3 & 0xFFFF) * D))[sub];
        float w0 = __half2float(__ushort_as_half((unsigned short)(p0 >> 16)));
        float w1 = __half2float(__ushort_as_half((unsigned short)(p1 >> 16)));
        float w2 = __half2float(__ushort_as_half((unsigned short)(p2 >> 16)));
        float w3 = __half2float(__ushort_as_half((unsigned short)(p3 >> 16)));
#pragma unroll
        for (int c = 0; c < 8; ++c)
            acc[c] += w0 * bf2f((unsigned short)v0[c]) + w1 * bf2f((unsigned short)v1[c])
                    + w2 * bf2f((unsigned short)v2[c]) + w3 * bf2f((unsigned short)v3[c]);
    }
    for (; i + 8 <= end; i += 8) {         // 8 rows in flight
        unsigned p0 = epay[i + qtr];
        unsigned p1 = epay[i + 4 + qtr];
        short8 v0 = ((const short8*)(h + (size_t)(p0 & 0xFFFF) * D))[sub];
        short8 v1 = ((const short8*)(h + (size_t)(p1 & 0xFFFF) * D))[sub];
        float w0 = __half2float(__ushort_as_half((unsigned short)(p0 >> 16)));
        float w1 = __half2float(__ushort_as_half((unsigned short)(p1 >> 16)));
#pragma unroll
        for (int c = 0; c < 8; ++c)
            acc[c] += w0 * bf2f((unsigned short)v0[c]) + w1 * bf2f((unsigned short)v1[c]);
    }
    for (; i + qtr < end; i += 4) {        // tail, per-quarter predicated
        unsigned p0 = epay[i + qtr];
        short8 v0 = ((const short8*)(h + (size_t)(p0 & 0xFFFF) * D))[sub];
        float w0 = __half2float(__ushort_as_half((unsigned short)(p0 >> 16)));
#pragma unroll
        for (int c = 0; c < 8; ++c)
            acc[c] += w0 * bf2f((unsigned short)v0[c]);
    }

    // combine quarters: after two steps lanes 0..15 hold the full sum
#pragma unroll
    for (int c = 0; c < 8; ++c) {
        acc[c] += __shfl(acc[c], (lane + 32) & 63, 64);
        acc[c] += __shfl(acc[c], (lane + 16) & 63, 64);
    }

    if (qtr == 0) {
        short8 xv = ((const short8*)(h + (size_t)node * D))[sub];
        short8 o;
#pragma unroll
        for (int c = 0; c < 8; ++c) {
            float v = acc[c] + EPSP1 * bf2f((unsigned short)xv[c]);
            o[c] = (short)f2bf(v);
        }
        ((short8*)(z + (size_t)node * D))[sub] = o;
    }
}

// ---------------------------------------------------------------------------
// Fused 2-layer MLP: out = act2( relu( A @ Wa ) @ Wb )
// Per block: 128 rows; 4 waves, each 32 rows x 128 cols.  GEMM1 -> LDS tile
// (bf16, stride TS) -> GEMM2.  16x16x32 bf16 MFMA; weights in packed
// B-fragment order (L2-served).
// ---------------------------------------------------------------------------
template<int RELU2, int OUT_F32>
__global__ __launch_bounds__(256) void mlp_fused(
    const unsigned short* __restrict__ A,
    const unsigned short* __restrict__ WpA,
    const unsigned short* __restrict__ WpB,
    void* __restrict__ outv, int n)
{
    __shared__ unsigned short t[128 * TS];   // 34 KB

    int tid  = threadIdx.x;
    int wave = tid >> 6;
    int lane = tid & 63;
    int quad = lane >> 4;
    int lc   = lane & 15;
    int rbase = blockIdx.x * 128 + wave * 32;
    int rloc  = wave * 32;

    const short8 zero8 = {0, 0, 0, 0, 0, 0, 0, 0};

    short8 a[2][4];
#pragma unroll
    for (int s = 0; s < 2; ++s) {
        int row = rbase + s * 16 + lc;
        const unsigned short* ap = A + (size_t)row * D;
#pragma unroll
        for (int kk = 0; kk < 4; ++kk)
            a[s][kk] = (row < n) ? *(const short8*)(ap + kk * 32 + quad * 8) : zero8;
    }

    f32x4 acc[2][8];
#pragma unroll
    for (int s = 0; s < 2; ++s)
#pragma unroll
        for (int c = 0; c < 8; ++c)
            acc[s][c] = (f32x4){0.f, 0.f, 0.f, 0.f};

#pragma unroll
    for (int cf = 0; cf < 8; ++cf) {
        short8 b[4];
#pragma unroll
        for (int kk = 0; kk < 4; ++kk)
            b[kk] = *(const short8*)(WpA + ((size_t)(kk * 4 + quad) * 128 + cf * 16 + lc) * 8);
#pragma unroll
        for (int kk = 0; kk < 4; ++kk) {
            acc[0][cf] = __builtin_amdgcn_mfma_f32_16x16x32_bf16(a[0][kk], b[kk], acc[0][cf], 0, 0, 0);
            acc[1][cf] = __builtin_amdgcn_mfma_f32_16x16x32_bf16(a[1][kk], b[kk], acc[1][cf], 0, 0, 0);
        }
    }

#pragma unroll
    for (int s = 0; s < 2; ++s)
#pragma unroll
        for (int reg = 0; reg < 4; ++reg) {
            int row = rloc + s * 16 + quad * 4 + reg;
#pragma unroll
            for (int cf = 0; cf < 8; ++cf)
                t[row * TS + cf * 16 + lc] = f2bf(fmaxf(acc[s][cf][reg], 0.f));
        }
    __syncthreads();

#pragma unroll
    for (int s = 0; s < 2; ++s) {
        int row = rloc + s * 16 + lc;
#pragma unroll
        for (int kk = 0; kk < 4; ++kk)
            a[s][kk] = *(const short8*)&t[row * TS + kk * 32 + quad * 8];
    }
#pragma unroll
    for (int s = 0; s < 2; ++s)
#pragma unroll
        for (int c = 0; c < 8; ++c)
            acc[s][c] = (f32x4){0.f, 0.f, 0.f, 0.f};

#pragma unroll
    for (int cf = 0; cf < 8; ++cf) {
        short8 b[4];
#pragma unroll
        for (int kk = 0; kk < 4; ++kk)
            b[kk] = *(const short8*)(WpB + ((size_t)(kk * 4 + quad) * 128 + cf * 16 + lc) * 8);
#pragma unroll
        for (int kk = 0; kk < 4; ++kk) {
            acc[0][cf] = __builtin_amdgcn_mfma_f32_16x16x32_bf16(a[0][kk], b[kk], acc[0][cf], 0, 0, 0);
            acc[1][cf] = __builtin_amdgcn_mfma_f32_16x16x32_bf16(a[1][kk], b[kk], acc[1][cf], 0, 0, 0);
        }
    }

#pragma unroll
    for (int s = 0; s < 2; ++s)
#pragma unroll
        for (int reg = 0; reg < 4; ++reg) {
            int row = rbase + s * 16 + quad * 4 + reg;
            if (row < n) {
#pragma unroll
                for (int cf = 0; cf < 8; ++cf) {
                    float v = acc[s][cf][reg];
                    if (RELU2) v = fmaxf(v, 0.f);
                    int col = cf * 16 + lc;
                    if (OUT_F32)
                        ((float*)outv)[(size_t)row * D + col] = v;
                    else
                        ((unsigned short*)outv)[(size_t)row * D + col] = f2bf(v);
                }
            }
        }
}

extern "C" void kernel_launch(void* const* d_in, const int* in_sizes, int n_in,
                              void* d_out, int out_size, void* d_ws, size_t ws_size,
                              hipStream_t stream) {
    const float* x   = (const float*)d_in[0];
    const int*   ei  = (const int*)d_in[1];
    const float* ew  = (const float*)d_in[2];
    const float* W1a = (const float*)d_in[3];
    const float* W1b = (const float*)d_in[4];
    const float* W2a = (const float*)d_in[5];
    const float* W2b = (const float*)d_in[6];
    float* out = (float*)d_out;

    int n_edges = in_sizes[2];                 // 800000
    const int* src = ei;
    const int* dst = ei + n_edges;

    size_t node_elems = (size_t)N_NODES * D;   // 6.4M
    unsigned short* hb = (unsigned short*)d_ws;        // 12.8 MB  bf16 node features
    unsigned short* zb = hb + node_elems;              // 12.8 MB  gather output
    unsigned short* wp = zb + node_elems;              // 4 x 32 KB packed weights
    unsigned* epay = (unsigned*)(wp + 4 * 16384);      // E x 4B final CSR payload
    uint2*  gstage = (uint2*)(epay + n_edges);         // NBUCK x CAP x 8B staging
    int*    gcnt   = (int*)(gstage + (size_t)NBUCK * CAP);  // NBUCK
    int*    off    = gcnt + NBUCK;                     // N+1

    int p1grid = (n_edges + P1E - 1) / P1E;             // 391
    int ggrid  = (N_NODES + 127) / 128;                 // 391
    int agrid  = (N_NODES + 3) / 4;                     // 12500
    int n4     = (int)(node_elems / 4);                 // 1.6M float4

    hipMemsetAsync(gcnt, 0, NBUCK * sizeof(int), stream);

    // ---- pass 1: edge bucketing
    pass1_bucket<<<p1grid, 256, 0, stream>>>(src, dst, ew, gcnt, gstage, n_edges);

    // ---- fused mid: CSR build | x->bf16 | weight pack (one dispatch)
    fused_mid<<<NBUCK + 782 + 16, 512, 0, stream>>>(
        gstage, gcnt, epay, off,
        x, hb, n4, W1a, W1b, W2a, W2b, wp);

    unsigned short* wp0 = wp;
    unsigned short* wp1 = wp + 16384;
    unsigned short* wp2 = wp + 2 * 16384;
    unsigned short* wp3 = wp + 3 * 16384;

    // ---- conv 1 (inter-conv relu fused into epilogue 2)
    gather_kernel<<<agrid, 256, 0, stream>>>(hb, off, epay, zb, N_NODES);
    mlp_fused<1, 0><<<ggrid, 256, 0, stream>>>(zb, wp0, wp1, hb, N_NODES);

    // ---- conv 2 (fp32 out, no final relu)
    gather_kernel<<<agrid, 256, 0, stream>>>(hb, off, epay, zb, N_NODES);
    mlp_fused<0, 1><<<ggrid, 256, 0, stream>>>(zb, wp2, wp3, out, N_NODES);
}